// Round 1
// baseline (32371.033 us; speedup 1.0000x reference)
//
#include <hip/hip_runtime.h>
#include <stdint.h>
#include <stddef.h>

typedef unsigned short ushort_t;
typedef __attribute__((ext_vector_type(8))) short short8;
typedef __attribute__((ext_vector_type(4))) float floatx4;

#define T_STEPS 1024
#define BATCH   128
#define HID     512
#define NBLK    256
#define NTHR    256
#define INV_KEEP 1.4285714285714286f

// grid barrier state:
//   [32]        = release generation (own 128B line)
//   [64..319]   = per-block arrival generation flags (no RMW contention)
__device__ unsigned g_sync[384];

struct Params {
  const float* xs;
  const float* Wih1; const float* Whh1; const float* bih1; const float* bhh1;
  const float* Wih2; const float* Whh2; const float* bih2; const float* bhh2;
  const float* mask;
  float* out;
  char* ws;
};

// Flag-array grid barrier: arrival = one plain store per block (parallel across
// 16 cachelines) instead of 256 serialized atomic RMWs on one line.
// Block 0's wave 0 aggregates and publishes the release word.
__device__ __forceinline__ void gridbar(unsigned gen) {
  __syncthreads();
  const int bid = blockIdx.x;
  if (bid == 0) {
    if (threadIdx.x < 64) {
      if (threadIdx.x == 0) {
        __threadfence();
        __hip_atomic_store(&g_sync[64 + 0], gen, __ATOMIC_RELAXED,
                           __HIP_MEMORY_SCOPE_AGENT);
      }
      const int base = 64 + (int)threadIdx.x * 4;
      for (;;) {
        bool ok = true;
#pragma unroll
        for (int k = 0; k < 4; ++k)
          ok &= (__hip_atomic_load(&g_sync[base + k], __ATOMIC_RELAXED,
                                   __HIP_MEMORY_SCOPE_AGENT) >= gen);
        if (__all(ok)) break;
        __builtin_amdgcn_s_sleep(1);
      }
      if (threadIdx.x == 0) {
        __threadfence();
        __hip_atomic_store(&g_sync[32], gen, __ATOMIC_RELEASE,
                           __HIP_MEMORY_SCOPE_AGENT);
      }
    }
  } else {
    if (threadIdx.x == 0) {
      __threadfence();
      __hip_atomic_store(&g_sync[64 + bid], gen, __ATOMIC_RELAXED,
                         __HIP_MEMORY_SCOPE_AGENT);
      while (__hip_atomic_load(&g_sync[32], __ATOMIC_RELAXED,
                               __HIP_MEMORY_SCOPE_AGENT) < gen)
        __builtin_amdgcn_s_sleep(1);
      __threadfence();
    }
  }
  __syncthreads();
}

__device__ __forceinline__ ushort_t f2b(float a) {  // RTNE f32->bf16
  unsigned u = __float_as_uint(a);
  u += 0x7FFFu + ((u >> 16) & 1u);
  return (ushort_t)(u >> 16);
}

// ws layout (bytes):
//   [0,       262144)  c1 fp32 [128][512]
//   [262144,  524288)  c2 fp32
//   [524288, 1048576)  h1: par{0,1} x {hi,lo} bf16 [128][512]  (par*262144 + which*131072)
//   [1048576,1572864)  h2: same
//   [1572864,2097152)  x slab: par{0,1} x {hi,lo} bf16 [128][512]
__global__ __launch_bounds__(NTHR, 1) void lstm_persist(Params p) {
  __shared__ __align__(16) ushort_t Wl[32768];  // hi at [0,16384), lo at [16384,32768)

  char* ws = p.ws;
  float* c1 = (float*)ws;
  float* c2 = (float*)(ws + 262144);
  auto H1HI = [&](int par) { return (ushort_t*)(ws + 524288 + par * 262144); };
  auto H1LO = [&](int par) { return (ushort_t*)(ws + 524288 + par * 262144 + 131072); };
  auto H2HI = [&](int par) { return (ushort_t*)(ws + 1048576 + par * 262144); };
  auto H2LO = [&](int par) { return (ushort_t*)(ws + 1048576 + par * 262144 + 131072); };
  auto XSHI = [&](int par) { return (ushort_t*)(ws + 1572864 + par * 262144); };
  auto XSLO = [&](int par) { return (ushort_t*)(ws + 1572864 + par * 262144 + 131072); };

  const int bid = blockIdx.x, tid = threadIdx.x;
  const int gtid = bid * NTHR + tid;            // 0..65535
  const int layer = bid >> 7, lb = bid & 127;   // block owns h-cols lb*4..lb*4+3
  const int lane = tid & 63, w = tid >> 6;
  const int jj = lane & 15, quad = lane >> 4;
  const int hg = (lb << 2) + (lane & 3);

  const float* Wih = layer ? p.Wih2 : p.Wih1;
  const float* Whh = layer ? p.Whh2 : p.Whh1;
  const float* bih = layer ? p.bih2 : p.bih1;
  const float* bhh = layer ? p.bhh2 : p.bhh1;
  float* cst = layer ? c2 : c1;

  // ---- one-time: weights -> LDS as bf16 hi/lo ----
  for (int i = tid; i < 16384; i += NTHR) {
    int kq = i >> 7, rem = i & 127, j = rem >> 3, e = rem & 7;
    int k = kq * 8 + e;
    int col = ((j >> 2) << 9) + (lb << 2) + (j & 3);  // gate*512 + lb*4 + ho
    float wv = (k < 512) ? Wih[col * 512 + k] : Whh[col * 512 + (k - 512)];
    unsigned uw = __float_as_uint(wv);
    Wl[i] = (ushort_t)(uw >> 16);                       // trunc hi
    float wf = __uint_as_float(uw & 0xFFFF0000u);
    Wl[16384 + i] = f2b(wv - wf);                       // RTNE lo
  }
  // ---- zero all state (c1,c2,h1,h2 both parities): bytes [0, 1572864) ----
  {
    uint4 zz = {0u, 0u, 0u, 0u};
    for (int i = gtid; i < 98304; i += NBLK * NTHR) ((uint4*)ws)[i] = zz;
  }
  // ---- convert x(t=0) into slab par 0 ----
  {
    float v = p.xs[gtid];
    unsigned uv = __float_as_uint(v);
    XSHI(0)[gtid] = (ushort_t)(uv >> 16);
    float hf = __uint_as_float(uv & 0xFFFF0000u);
    XSLO(0)[gtid] = f2b(v - hf);
  }
  // ---- per-lane constants: bias sum and dropout factors ----
  float bsum;
  {
    int colW = ((jj >> 2) << 9) + (lb << 2) + (jj & 3);
    bsum = bih[colW] + bhh[colW];
  }
  float dpre[2][4];
#pragma unroll
  for (int mt = 0; mt < 2; ++mt)
#pragma unroll
    for (int e = 0; e < 4; ++e) {
      int r = w * 32 + mt * 16 + quad * 4 + e;
      dpre[mt][e] = p.mask[r * 512 + hg] * INV_KEEP;
    }

  unsigned gen = 1;
  gridbar(gen++);

  const int rowbyte = ((w * 32 + jj) * 512 + quad * 8) * 2;  // mt=0 A-frag byte offset

#pragma unroll 1
  for (unsigned u = 0; u <= T_STEPS; ++u) {
    // ---- convert x(u+1) into slab (u+1)&1 (each thread: 1 element) ----
    if (u <= T_STEPS - 2) {
      float v = p.xs[(size_t)(u + 1) * 65536 + gtid];
      unsigned uv = __float_as_uint(v);
      int pn = (u + 1) & 1;
      XSHI(pn)[gtid] = (ushort_t)(uv >> 16);
      float hf = __uint_as_float(uv & 0xFFFF0000u);
      XSLO(pn)[gtid] = f2b(v - hf);
    }

    const bool active = layer ? (u >= 1) : (u < T_STEPS);
    if (active) {
      const int t = layer ? (int)u - 1 : (int)u;
      const int pu = (int)u & 1, pv = pu ^ 1;
      // A sources: low half (k<512) and high half (k>=512), hi/lo each
      const ushort_t *aLoHi, *aLoLo, *aHiHi, *aHiLo;
      ushort_t *whHi, *whLo;
      if (layer == 0) {
        aLoHi = XSHI(pu); aLoLo = XSLO(pu);    // x(u)
        aHiHi = H1HI(pv); aHiLo = H1LO(pv);    // h1(u-1)
        whHi = H1HI(pu);  whLo = H1LO(pu);     // write h1(u)
      } else {
        aLoHi = H1HI(pv); aLoLo = H1LO(pv);    // h1(u-1) = h1(t)
        aHiHi = H2HI(pu); aHiLo = H2LO(pu);    // h2(u-2) = h2(t-1)
        whHi = H2HI(pv);  whLo = H2LO(pv);     // write h2(t)
      }

      floatx4 acc[2];
      acc[0] = (floatx4){bsum, bsum, bsum, bsum};
      acc[1] = acc[0];

      auto ldchunk = [&](int c, uint4* dst) {
        const char* bh = (const char*)((c < 8) ? aLoHi : aHiHi);
        const char* bl = (const char*)((c < 8) ? aLoLo : aHiLo);
        int kb = (c & 7) * 128;
#pragma unroll
        for (int ks = 0; ks < 2; ++ks)
#pragma unroll
          for (int mt = 0; mt < 2; ++mt) {
            int off = rowbyte + mt * 16384 + kb + ks * 64;
            dst[(ks * 2 + mt) * 2 + 0] = *(const uint4*)(bh + off);
            dst[(ks * 2 + mt) * 2 + 1] = *(const uint4*)(bl + off);
          }
      };

      uint4 ring[3][8];
      ldchunk(0, ring[0]);
      ldchunk(1, ring[1]);
#pragma unroll
      for (int c = 0; c < 16; ++c) {
        if (c < 14) ldchunk(c + 2, ring[(c + 2) % 3]);
        uint4* cur = ring[c % 3];
#pragma unroll
        for (int ks = 0; ks < 2; ++ks) {
          int o = ((c * 8 + ks * 4 + quad) * 16 + jj) * 8;
          short8 bhf = *(const short8*)&Wl[o];
          short8 blf = *(const short8*)&Wl[16384 + o];
#pragma unroll
          for (int mt = 0; mt < 2; ++mt) {
            short8 ahf = *(const short8*)&cur[(ks * 2 + mt) * 2 + 0];
            short8 alf = *(const short8*)&cur[(ks * 2 + mt) * 2 + 1];
            acc[mt] = __builtin_amdgcn_mfma_f32_16x16x32_bf16(ahf, bhf, acc[mt], 0, 0, 0);
            acc[mt] = __builtin_amdgcn_mfma_f32_16x16x32_bf16(ahf, blf, acc[mt], 0, 0, 0);
            acc[mt] = __builtin_amdgcn_mfma_f32_16x16x32_bf16(alf, bhf, acc[mt], 0, 0, 0);
          }
        }
      }

      // ---- epilogue: shuffle-gather gates, cell update, store h hi/lo + c + out ----
      const int sb = (lane & 48) | (lane & 3);
#pragma unroll
      for (int mt = 0; mt < 2; ++mt)
#pragma unroll
        for (int e = 0; e < 4; ++e) {
          float v = acc[mt][e];
          float gi = __shfl(v, sb + 0, 64);
          float gf = __shfl(v, sb + 4, 64);
          float gg = __shfl(v, sb + 8, 64);
          float go = __shfl(v, sb + 12, 64);
          float si = 1.f / (1.f + __expf(-gi));
          float sf = 1.f / (1.f + __expf(-gf));
          float so = 1.f / (1.f + __expf(-go));
          float tg = 2.f / (1.f + __expf(-2.f * gg)) - 1.f;
          int r = w * 32 + mt * 16 + quad * 4 + e;
          int ci = r * 512 + hg;
          float cold = cst[ci];
          float cn = sf * cold + si * tg;
          float tc = 2.f / (1.f + __expf(-2.f * cn)) - 1.f;
          float hn = so * tc;
          float d = dpre[mt][e];
          hn *= d; cn *= d;
          cst[ci] = cn;
          unsigned uh = __float_as_uint(hn);
          whHi[ci] = (ushort_t)(uh >> 16);
          float hf = __uint_as_float(uh & 0xFFFF0000u);
          whLo[ci] = f2b(hn - hf);
          if (layer) p.out[(size_t)t * 65536 + ci] = hn;
        }
    }
    if (u < T_STEPS) gridbar(gen++);  // last iteration: kernel exit is the sync
  }
}

extern "C" void kernel_launch(void* const* d_in, const int* in_sizes, int n_in,
                              void* d_out, int out_size, void* d_ws, size_t ws_size,
                              hipStream_t stream) {
  (void)in_sizes; (void)n_in; (void)out_size; (void)ws_size;
  Params p;
  p.xs   = (const float*)d_in[0];
  p.Wih1 = (const float*)d_in[1];
  p.Whh1 = (const float*)d_in[2];
  p.bih1 = (const float*)d_in[3];
  p.bhh1 = (const float*)d_in[4];
  p.Wih2 = (const float*)d_in[5];
  p.Whh2 = (const float*)d_in[6];
  p.bih2 = (const float*)d_in[7];
  p.bhh2 = (const float*)d_in[8];
  p.mask = (const float*)d_in[9];
  p.out  = (float*)d_out;
  p.ws   = (char*)d_ws;   // needs 2 MiB

  void* sym = nullptr;
  hipGetSymbolAddress(&sym, HIP_SYMBOL(g_sync));
  hipMemsetAsync(sym, 0, 384 * sizeof(unsigned), stream);

  void* args[] = { &p };
  hipLaunchCooperativeKernel(reinterpret_cast<void*>(lstm_persist),
                             dim3(NBLK), dim3(NTHR), args, 0, stream);
}

// Round 3
// 28412.363 us; speedup vs baseline: 1.1393x; 1.1393x over previous
//
#include <hip/hip_runtime.h>
#include <stdint.h>
#include <stddef.h>

typedef unsigned short ushort_t;
typedef __attribute__((ext_vector_type(8))) short short8;
typedef __attribute__((ext_vector_type(4))) float floatx4;

#define T_STEPS 1024
#define BATCH   128
#define HID     512
#define NBLK    256
#define NTHR    256
#define INV_KEEP 1.4285714285714286f

// grid barrier state:
//   [32]        = release generation (own 128B line)
//   [64..319]   = per-block arrival generation flags (no RMW contention)
__device__ unsigned g_sync[384];

struct Params {
  const float* xs;
  const float* Wih1; const float* Whh1; const float* bih1; const float* bhh1;
  const float* Wih2; const float* Whh2; const float* bih2; const float* bhh2;
  const float* mask;
  float* out;
  char* ws;
};

// Flag-array grid barrier: arrival = one plain store per block (parallel across
// 16 cachelines). Block 0's wave 0 aggregates and publishes the release word.
__device__ __forceinline__ void gridbar(unsigned gen) {
  __syncthreads();
  const int bid = blockIdx.x;
  if (bid == 0) {
    if (threadIdx.x < 64) {
      if (threadIdx.x == 0) {
        __threadfence();
        __hip_atomic_store(&g_sync[64 + 0], gen, __ATOMIC_RELAXED,
                           __HIP_MEMORY_SCOPE_AGENT);
      }
      const int base = 64 + (int)threadIdx.x * 4;
      for (;;) {
        bool ok = true;
#pragma unroll
        for (int k = 0; k < 4; ++k)
          ok &= (__hip_atomic_load(&g_sync[base + k], __ATOMIC_RELAXED,
                                   __HIP_MEMORY_SCOPE_AGENT) >= gen);
        if (__all(ok)) break;
        __builtin_amdgcn_s_sleep(1);
      }
      if (threadIdx.x == 0) {
        __threadfence();
        __hip_atomic_store(&g_sync[32], gen, __ATOMIC_RELEASE,
                           __HIP_MEMORY_SCOPE_AGENT);
      }
    }
  } else {
    if (threadIdx.x == 0) {
      __threadfence();
      __hip_atomic_store(&g_sync[64 + bid], gen, __ATOMIC_RELAXED,
                         __HIP_MEMORY_SCOPE_AGENT);
      while (__hip_atomic_load(&g_sync[32], __ATOMIC_RELAXED,
                               __HIP_MEMORY_SCOPE_AGENT) < gen)
        __builtin_amdgcn_s_sleep(1);
      __threadfence();
    }
  }
  __syncthreads();
}

__device__ __forceinline__ ushort_t f2b(float a) {  // RTNE f32->bf16
  unsigned u = __float_as_uint(a);
  u += 0x7FFFu + ((u >> 16) & 1u);
  return (ushort_t)(u >> 16);
}

// ws layout (bytes):
//   [0,       524288)  (unused; formerly c1/c2 — c now lives in registers)
//   [524288, 1048576)  h1: par{0,1} x {hi,lo} bf16 [128][512]  (par*262144 + which*131072)
//   [1048576,1572864)  h2: same
//   [1572864,2097152)  x slab: par{0,1} x {hi,lo} bf16 [128][512]
//
// Block decomposition (256 blocks): layer = bid>>7; c8 = (bid&127)>>1 owns
// 8 h-cols [c8*8, c8*8+8); bhalf = bid&1 owns 64 batch rows [bhalf*64, ..+64).
// Per-block A read = 256 KB/step (was 512 KB) -> total LLC read traffic halves.
//
// NOTE: init zeroing must cover ONLY the h slabs [524288, 1572864). The x slab
// is written (x(t=0)) by other blocks concurrently before the first barrier —
// zeroing it here is a cross-block race (round-2 bug, absmax 1.17).
__global__ __launch_bounds__(NTHR, 1) void lstm_persist(Params p) {
  extern __shared__ ushort_t Wl[];  // 128 KB: hi at [0,32768), lo at [32768,65536)

  char* ws = p.ws;
  auto H1HI = [&](int par) { return (ushort_t*)(ws + 524288 + par * 262144); };
  auto H1LO = [&](int par) { return (ushort_t*)(ws + 524288 + par * 262144 + 131072); };
  auto H2HI = [&](int par) { return (ushort_t*)(ws + 1048576 + par * 262144); };
  auto H2LO = [&](int par) { return (ushort_t*)(ws + 1048576 + par * 262144 + 131072); };
  auto XSHI = [&](int par) { return (ushort_t*)(ws + 1572864 + par * 262144); };
  auto XSLO = [&](int par) { return (ushort_t*)(ws + 1572864 + par * 262144 + 131072); };

  const int bid = blockIdx.x, tid = threadIdx.x;
  const int gtid = bid * NTHR + tid;            // 0..65535
  const int layer = bid >> 7;
  const int c8 = (bid & 127) >> 1;              // col-group: 8 h-cols
  const int bhalf = bid & 1;                    // batch half: 64 rows
  const int lane = tid & 63, w = tid >> 6;      // 4 waves, 16 batch rows each
  const int jj = lane & 15, quad = lane >> 4;
  const int rbase = bhalf * 64 + w * 16;

  const float* Wih = layer ? p.Wih2 : p.Wih1;
  const float* Whh = layer ? p.Whh2 : p.Whh1;
  const float* bih = layer ? p.bih2 : p.bih1;
  const float* bhh = layer ? p.bhh2 : p.bhh1;

  // ---- one-time: weights -> LDS as bf16 hi/lo (32 gate-cols x 1024 k) ----
  for (int i = tid; i < 32768; i += NTHR) {
    int e = i & 7, jjw = (i >> 3) & 15, ntw = (i >> 7) & 1, kg = i >> 8;
    int k = kg * 8 + e;
    int col = ((jjw >> 2) << 9) + c8 * 8 + ntw * 4 + (jjw & 3);  // gate*512 + hcol
    float wv = (k < 512) ? Wih[col * 512 + k] : Whh[col * 512 + (k - 512)];
    unsigned uw = __float_as_uint(wv);
    Wl[i] = (ushort_t)(uw >> 16);                       // trunc hi
    float wf = __uint_as_float(uw & 0xFFFF0000u);
    Wl[32768 + i] = f2b(wv - wf);                       // RTNE lo
  }
  // ---- zero h slabs ONLY (both parities): bytes [524288, 1572864) ----
  {
    uint4 zz = {0u, 0u, 0u, 0u};
    uint4* dst = (uint4*)(ws + 524288);
    for (int i = gtid; i < 65536; i += NBLK * NTHR) dst[i] = zz;
  }
  // ---- convert x(t=0) into slab par 0 ----
  {
    float v = p.xs[gtid];
    unsigned uv = __float_as_uint(v);
    XSHI(0)[gtid] = (ushort_t)(uv >> 16);
    float hf = __uint_as_float(uv & 0xFFFF0000u);
    XSLO(0)[gtid] = f2b(v - hf);
  }
  // ---- per-lane constants: bias sums and dropout factors; c in registers ----
  float bsum[2];
#pragma unroll
  for (int nt = 0; nt < 2; ++nt) {
    int colW = ((jj >> 2) << 9) + c8 * 8 + nt * 4 + (jj & 3);
    bsum[nt] = bih[colW] + bhh[colW];
  }
  float dpre[2][4];
  float creg[2][4];
#pragma unroll
  for (int nt = 0; nt < 2; ++nt)
#pragma unroll
    for (int e = 0; e < 4; ++e) {
      int r = rbase + quad * 4 + e;
      int hgc = c8 * 8 + nt * 4 + (lane & 3);
      dpre[nt][e] = p.mask[r * 512 + hgc] * INV_KEEP;
      creg[nt][e] = 0.f;
    }

  unsigned gen = 1;
  gridbar(gen++);

  const int rowbyte = ((rbase + jj) * 512 + quad * 8) * 2;  // A-frag byte offset

#pragma unroll 1
  for (unsigned u = 0; u <= T_STEPS; ++u) {
    // ---- convert x(u+1) into slab (u+1)&1 (each thread: 1 element) ----
    if (u <= T_STEPS - 2) {
      float v = p.xs[(size_t)(u + 1) * 65536 + gtid];
      unsigned uv = __float_as_uint(v);
      int pn = (u + 1) & 1;
      XSHI(pn)[gtid] = (ushort_t)(uv >> 16);
      float hf = __uint_as_float(uv & 0xFFFF0000u);
      XSLO(pn)[gtid] = f2b(v - hf);
    }

    const bool active = layer ? (u >= 1) : (u < T_STEPS);
    if (active) {
      const int t = layer ? (int)u - 1 : (int)u;
      const int pu = (int)u & 1, pv = pu ^ 1;
      // A sources: low half (k<512) and high half (k>=512), hi/lo each
      const ushort_t *aLoHi, *aLoLo, *aHiHi, *aHiLo;
      ushort_t *whHi, *whLo;
      if (layer == 0) {
        aLoHi = XSHI(pu); aLoLo = XSLO(pu);    // x(u)
        aHiHi = H1HI(pv); aHiLo = H1LO(pv);    // h1(u-1)
        whHi = H1HI(pu);  whLo = H1LO(pu);     // write h1(u)
      } else {
        aLoHi = H1HI(pv); aLoLo = H1LO(pv);    // h1(u-1) = h1(t)
        aHiHi = H2HI(pu); aHiLo = H2LO(pu);    // h2(u-2) = h2(t-1)
        whHi = H2HI(pv);  whLo = H2LO(pv);     // write h2(t)
      }

      floatx4 acc[2];
      acc[0] = (floatx4){bsum[0], bsum[0], bsum[0], bsum[0]};
      acc[1] = (floatx4){bsum[1], bsum[1], bsum[1], bsum[1]};

      auto ldchunk = [&](int c, uint4* dst) {
        const char* bh = (const char*)((c < 8) ? aLoHi : aHiHi);
        const char* bl = (const char*)((c < 8) ? aLoLo : aHiLo);
        int kb = (c & 7) * 128;
#pragma unroll
        for (int ks = 0; ks < 2; ++ks) {
          int off = rowbyte + kb + ks * 64;
          dst[ks * 2 + 0] = *(const uint4*)(bh + off);
          dst[ks * 2 + 1] = *(const uint4*)(bl + off);
        }
      };

      uint4 ring[4][4];
      ldchunk(0, ring[0]);
      ldchunk(1, ring[1]);
      ldchunk(2, ring[2]);
#pragma unroll
      for (int c = 0; c < 16; ++c) {
        if (c < 13) ldchunk(c + 3, ring[(c + 3) & 3]);
        uint4* cur = ring[c & 3];
#pragma unroll
        for (int ks = 0; ks < 2; ++ks) {
          short8 ahf = *(const short8*)&cur[ks * 2 + 0];
          short8 alf = *(const short8*)&cur[ks * 2 + 1];
#pragma unroll
          for (int nt = 0; nt < 2; ++nt) {
            int o = (((c * 8 + ks * 4 + quad) * 2 + nt) * 16 + jj) * 8;
            short8 bhf = *(const short8*)&Wl[o];
            short8 blf = *(const short8*)&Wl[32768 + o];
            acc[nt] = __builtin_amdgcn_mfma_f32_16x16x32_bf16(ahf, bhf, acc[nt], 0, 0, 0);
            acc[nt] = __builtin_amdgcn_mfma_f32_16x16x32_bf16(ahf, blf, acc[nt], 0, 0, 0);
            acc[nt] = __builtin_amdgcn_mfma_f32_16x16x32_bf16(alf, bhf, acc[nt], 0, 0, 0);
          }
        }
      }

      // ---- epilogue: shuffle-gather gates, cell update (c in regs), store ----
      const int sb = (lane & 48) | (lane & 3);
#pragma unroll
      for (int nt = 0; nt < 2; ++nt)
#pragma unroll
        for (int e = 0; e < 4; ++e) {
          float v = acc[nt][e];
          float gi = __shfl(v, sb + 0, 64);
          float gf = __shfl(v, sb + 4, 64);
          float gg = __shfl(v, sb + 8, 64);
          float go = __shfl(v, sb + 12, 64);
          float si = 1.f / (1.f + __expf(-gi));
          float sf = 1.f / (1.f + __expf(-gf));
          float so = 1.f / (1.f + __expf(-go));
          float tg = 2.f / (1.f + __expf(-2.f * gg)) - 1.f;
          int r = rbase + quad * 4 + e;
          int hgc = c8 * 8 + nt * 4 + (lane & 3);
          int ci = r * 512 + hgc;
          float cn = sf * creg[nt][e] + si * tg;
          float tc = 2.f / (1.f + __expf(-2.f * cn)) - 1.f;
          float hn = so * tc;
          float d = dpre[nt][e];
          hn *= d; cn *= d;
          creg[nt][e] = cn;
          unsigned uh = __float_as_uint(hn);
          whHi[ci] = (ushort_t)(uh >> 16);
          float hf = __uint_as_float(uh & 0xFFFF0000u);
          whLo[ci] = f2b(hn - hf);
          if (layer) p.out[(size_t)t * 65536 + ci] = hn;
        }
    }
    if (u < T_STEPS) gridbar(gen++);  // last iteration: kernel exit is the sync
  }
}

extern "C" void kernel_launch(void* const* d_in, const int* in_sizes, int n_in,
                              void* d_out, int out_size, void* d_ws, size_t ws_size,
                              hipStream_t stream) {
  (void)in_sizes; (void)n_in; (void)out_size; (void)ws_size;
  Params p;
  p.xs   = (const float*)d_in[0];
  p.Wih1 = (const float*)d_in[1];
  p.Whh1 = (const float*)d_in[2];
  p.bih1 = (const float*)d_in[3];
  p.bhh1 = (const float*)d_in[4];
  p.Wih2 = (const float*)d_in[5];
  p.Whh2 = (const float*)d_in[6];
  p.bih2 = (const float*)d_in[7];
  p.bhh2 = (const float*)d_in[8];
  p.mask = (const float*)d_in[9];
  p.out  = (float*)d_out;
  p.ws   = (char*)d_ws;   // needs 2 MiB

  static bool attr_done = false;
  if (!attr_done) {
    (void)hipFuncSetAttribute(reinterpret_cast<const void*>(lstm_persist),
                              hipFuncAttributeMaxDynamicSharedMemorySize, 131072);
    attr_done = true;
  }

  void* sym = nullptr;
  hipGetSymbolAddress(&sym, HIP_SYMBOL(g_sync));
  hipMemsetAsync(sym, 0, 384 * sizeof(unsigned), stream);

  void* args[] = { &p };
  hipLaunchCooperativeKernel(reinterpret_cast<void*>(lstm_persist),
                             dim3(NBLK), dim3(NTHR), args, 131072, stream);
}